// Round 12
// baseline (2292.361 us; speedup 1.0000x reference)
//
#include <hip/hip_runtime.h>
#include <math.h>

#define HID 512
#define BAT 512
#define NIN 128
#define TST 128
#define HOR 32
#define SBZ ((size_t)BAT * HID)
#define SL 262144            // shorts per h-slot (512x512 bf16)
#define SLB 524288           // bytes per h-slot

using bf16x8 = __attribute__((ext_vector_type(8))) __bf16;
using f32x4  = __attribute__((ext_vector_type(4))) float;

__device__ __forceinline__ float sigf(float x) { return 1.0f / (1.0f + __expf(-x)); }
__device__ __forceinline__ float tanhfast(float x) { return 1.0f - 2.0f / (__expf(2.0f * x) + 1.0f); }

__device__ __forceinline__ short f2bf(float x) {
    union { float f; unsigned u; } v; v.f = x;
    unsigned r = (v.u + 0x7FFFu + ((v.u >> 16) & 1u)) >> 16;
    return (short)r;
}
__device__ __forceinline__ float bf2f(short s) {
    union { unsigned u; float f; } v; v.u = ((unsigned)(unsigned short)s) << 16;
    return v.f;
}
__device__ __forceinline__ bf16x8 asbf(f32x4 v) {
    union { f32x4 f; bf16x8 b; } u; u.f = v; return u.b;
}

// Fence-free hierarchical grid barrier for 128 blocks (16 leaves x 8).
__device__ __forceinline__ void gbar(unsigned* bar, int bid, unsigned ep) {
    __syncthreads();
    if (threadIdx.x == 0) {
        unsigned* leaf = bar + ((unsigned)bid >> 3) * 32;
        unsigned* root = bar + 1024;
        unsigned* flag = bar + 1056;
        unsigned old = __hip_atomic_fetch_add(leaf, 1u, __ATOMIC_RELAXED, __HIP_MEMORY_SCOPE_AGENT);
        if (old == 8u * ep - 1u) {
            unsigned ro = __hip_atomic_fetch_add(root, 1u, __ATOMIC_RELAXED, __HIP_MEMORY_SCOPE_AGENT);
            if (ro == 16u * ep - 1u)
                __hip_atomic_store(flag, ep, __ATOMIC_RELAXED, __HIP_MEMORY_SCOPE_AGENT);
        }
        int spin = 0;
        while (__hip_atomic_load(flag, __ATOMIC_RELAXED, __HIP_MEMORY_SCOPE_AGENT) < ep) {
            __builtin_amdgcn_s_sleep(1);
            if (((++spin) & 63) == 0)
                __hip_atomic_fetch_add(flag, 0u, __ATOMIC_RELAXED, __HIP_MEMORY_SCOPE_AGENT);
        }
    }
    __syncthreads();
}

// ---------------- prep kernels (r11-verified) ----------------

__global__ __launch_bounds__(256) void prep_w(const float* __restrict__ Wih,
                                              const float* __restrict__ Whh,
                                              short* __restrict__ W2, int Kx, int Kp) {
    size_t i = (size_t)blockIdx.x * 256 + threadIdx.x;
    if (i >= (size_t)2048 * Kp) return;
    int np = (int)(i / Kp), kp = (int)(i % Kp);
    int u = np >> 2, gate = np & 3;
    int on = gate * HID + u;
    float w = (kp < Kx) ? Wih[(size_t)on * Kx + kp] : Whh[(size_t)on * HID + (kp - Kx)];
    W2[i] = f2bf(w);
}

__global__ __launch_bounds__(256) void prep_x(const float* __restrict__ window,
                                              short* __restrict__ X2t) {
    size_t i = (size_t)blockIdx.x * 256 + threadIdx.x;
    if (i >= (size_t)TST * BAT * NIN) return;
    int n = (int)(i & 127);
    int b = (int)((i >> 7) & 511);
    int t = (int)(i >> 16);
    float x = window[(size_t)b * (TST * NIN) + (size_t)t * NIN + n];
    int rg = b >> 4;
    int l = (b & 15) + (((n >> 3) & 3) << 4);
    int e = n & 7;
    size_t base = (size_t)t * 65536 + ((size_t)(rg * 4 + (n >> 5)) << 9) + l * 8 + e;
    X2t[base] = f2bf(x);
}

__global__ __launch_bounds__(256) void prep_fuse(const float* __restrict__ Wc1i,
                                                 const float* __restrict__ Wp,
                                                 float* __restrict__ Wfuse) {
    size_t i = (size_t)blockIdx.x * 256 + threadIdx.x;
    if (i >= (size_t)2048 * 512) return;
    int on = (int)(i >> 9), k = (int)(i & 511);
    float s = 0.f;
    for (int n = 0; n < NIN; ++n) s += Wc1i[(size_t)on * NIN + n] * Wp[(size_t)n * HID + k];
    Wfuse[i] = s;
}

__global__ __launch_bounds__(256) void prep_badd(const float* __restrict__ Wc1i,
                                                 const float* __restrict__ bp,
                                                 float* __restrict__ badd) {
    int on = blockIdx.x * 256 + threadIdx.x;
    if (on >= 2048) return;
    float s = 0.f;
    for (int n = 0; n < NIN; ++n) s += Wc1i[(size_t)on * NIN + n] * bp[n];
    badd[on] = s;
}

__global__ __launch_bounds__(256) void prep_bias(const float* __restrict__ bih,
                                                 const float* __restrict__ bhh,
                                                 const float* __restrict__ badd,
                                                 float* __restrict__ bout) {
    int np = blockIdx.x * 256 + threadIdx.x;
    if (np >= 2048) return;
    int on = (np & 3) * HID + (np >> 2);
    float v = bih[on] + bhh[on];
    if (badd) v += badd[on];
    bout[np] = v;
}

__global__ __launch_bounds__(256) void prep_wp(const float* __restrict__ Wp,
                                               short* __restrict__ W2p) {
    int i = blockIdx.x * 256 + threadIdx.x;
    if (i >= 128 * 512) return;
    W2p[i] = f2bf(Wp[i]);
}

// ---------------- device building blocks ----------------

template<bool SC>
__device__ __forceinline__ void gl16(f32x4& q, const char* p) {
    if constexpr (SC)
        asm volatile("global_load_dwordx4 %0, %1, off sc0 sc1" : "=v"(q) : "v"(p));
    else
        asm volatile("global_load_dwordx4 %0, %1, off" : "=v"(q) : "v"(p));
}

// 32-row resident W (for proj): lds[j*512 + r*16]
__device__ __forceinline__ void load_wres32(char* lds, const short* Wg, int K) {
    const int tid = threadIdx.x;
    const int r = tid >> 4;
    const int cnt = K >> 7;
    const int jb = (tid & 15) * cnt;
    for (int q = 0; q < cnt; ++q) {
        int j = jb + q;
        bf16x8 v = *(const bf16x8*)(Wg + (size_t)r * K + j * 8);
        *(bf16x8*)(lds + j * 512 + r * 16) = v;
    }
}

// 64-row resident W (persist): lds[j*1024 + r*16], r=0..63
__device__ __forceinline__ void load_wres64(char* lds, const short* Wg, int K) {
    const int r = threadIdx.x >> 3, jg = threadIdx.x & 7;
    for (int q = 0; q < (K >> 6); ++q) {
        int j = jg + (q << 3);
        bf16x8 v = *(const bf16x8*)(Wg + (size_t)r * K + j * 8);
        *(bf16x8*)(lds + (size_t)j * 1024 + r * 16) = v;
    }
}

// mask prefetch (asm loads BEFORE counted loads: oldest-first drain keeps vmcnt math exact)
__device__ __forceinline__ void pre_mask_asm(const float* msk, int mrow, int u0, float o[4]) {
    const int lane = threadIdx.x & 63;
    const float* p = msk + (size_t)(mrow + ((lane >> 3) << 2)) * HID + u0 + (lane & 7);
#pragma unroll
    for (int r = 0; r < 4; ++r)
        asm volatile("global_load_dword %0, %1, off" : "=v"(o[r]) : "v"(p + (size_t)r * HID));
}

// Wave GEMM 32(m) x 64(n') over chunked A; counted-vmcnt depth D=12; W from LDS (64-row).
template<int C0, int C1, bool SC>
__device__ __forceinline__ void gemm64(
    const char* wres, const short* a0t, const short* a1t,
    int mb, f32x4 acc[2][4])
{
    constexpr int NKC = C0 + C1;
    constexpr int D = 12;
    const int lane = threadIdx.x & 63;
    const int arow = lane & 15, akg = lane >> 4;
    const size_t lb = (size_t)lane << 4;
    const char* base0 = (const char*)a0t;
    const char* base1 = (const char*)a1t;
    auto cptr = [&](int kc, int fh) -> const char* {
        return (kc < C0)
            ? base0 + (((size_t)(mb * 2 + fh) * C0 + kc) << 10) + lb
            : base1 + (((size_t)(mb * 2 + fh) * C1 + (kc - C0)) << 10) + lb;
    };
    f32x4 q0[D], q1[D];
#pragma unroll
    for (int i = 0; i < D; ++i) {
        gl16<SC>(q0[i], cptr(i, 0));
        gl16<SC>(q1[i], cptr(i, 1));
    }
#pragma unroll
    for (int kc = 0; kc < NKC; ++kc) {
        const int sl = kc % D;
        asm volatile("s_waitcnt vmcnt(%2)"
                     : "+v"(q0[sl]), "+v"(q1[sl])
                     : "i"((2 * ((NKC - kc) < D ? (NKC - kc) : D)) - 2));
        const bf16x8 fa0 = asbf(q0[sl]);
        const bf16x8 fa1 = asbf(q1[sl]);
        if (kc + D < NKC) {
            gl16<SC>(q0[sl], cptr(kc + D, 0));
            gl16<SC>(q1[sl], cptr(kc + D, 1));
        }
        const char* wrow = wres + (size_t)((kc << 2) + akg) * 1024;
        bf16x8 fb[4];
#pragma unroll
        for (int nj = 0; nj < 4; ++nj)
            fb[nj] = *(const bf16x8*)(wrow + ((nj * 16 + arow) << 4));
#pragma unroll
        for (int nj = 0; nj < 4; ++nj) {
            acc[0][nj] = __builtin_amdgcn_mfma_f32_16x16x32_bf16(fa0, fb[nj], acc[0][nj], 0, 0, 0);
            acc[1][nj] = __builtin_amdgcn_mfma_f32_16x16x32_bf16(fa1, fb[nj], acc[1][nj], 0, 0, 0);
        }
    }
    asm volatile("s_waitcnt vmcnt(0)");
}

// Wave LSTM epilogue over 32 rows x 64 n' in two 32-wide passes (r11-verified body).
__device__ __forceinline__ void cell_epi64(
    char* scrw, f32x4 acc[2][4], float creg[2][4], int mb, int np0,
    const float* bias_p, const float* mh, const float* mc, const float* ma,
    short* h_out, short* h_aux)
{
    const int lane = threadIdx.x & 63;
#pragma unroll
    for (int p = 0; p < 2; ++p) {
        const int np0p = np0 + (p << 5);
#pragma unroll
        for (int mi = 0; mi < 2; ++mi)
#pragma unroll
            for (int nj = 0; nj < 2; ++nj) {
                const int row = mi * 16 + ((lane >> 4) << 2);
                const int col = nj * 16 + (lane & 15);
#pragma unroll
                for (int r = 0; r < 4; ++r)
                    *(float*)(scrw + (row + r) * 128 + (col << 2)) = acc[mi][p * 2 + nj][r];
            }
        asm volatile("s_waitcnt lgkmcnt(0)" ::: "memory");
        const int ul = lane & 7, g = lane >> 3;
        f32x4 gv[4];
#pragma unroll
        for (int r = 0; r < 4; ++r)
            gv[r] = *(const f32x4*)(scrw + ((g << 2) + r) * 128 + (ul << 4));
        asm volatile("s_waitcnt lgkmcnt(0)" ::: "memory");
        const float4 bs = *(const float4*)(bias_p + np0p + (ul << 2));
#pragma unroll
        for (int r = 0; r < 4; ++r) {
            const int m = (g << 2) + r;
            const int fh = m >> 4, r16 = m & 15;
            const float gi = gv[r][0] + bs.x, gf = gv[r][1] + bs.y;
            const float gg = gv[r][2] + bs.z, go = gv[r][3] + bs.w;
            const float cn = sigf(gf) * creg[p][r] + sigf(gi) * tanhfast(gg);
            const float h  = sigf(go) * tanhfast(cn);
            creg[p][r] = mc ? cn * mc[p * 4 + r] : cn;
            const float hm = mh ? h * mh[p * 4 + r] : h;
            const int idx2 = (r16 << 3) + ul;
            *(short*)(scrw + fh * 256 + idx2 * 2) = f2bf(hm);
            if (h_aux)
                *(short*)(scrw + 512 + fh * 256 + idx2 * 2) = f2bf(h * ma[p * 4 + r]);
        }
        const int u0p = np0p >> 2;
        const int c_hi = u0p >> 5, gsub = (u0p >> 3) & 3;
        unsigned vmain[2], vaux[2];
#pragma unroll
        for (int s = 0; s < 2; ++s)
            vmain[s] = *(const unsigned*)(scrw + s * 256 + (lane << 2));
        if (h_aux)
#pragma unroll
            for (int s = 0; s < 2; ++s)
                vaux[s] = *(const unsigned*)(scrw + 512 + s * 256 + (lane << 2));
        asm volatile("s_waitcnt lgkmcnt(0)" ::: "memory");
#pragma unroll
        for (int s = 0; s < 2; ++s) {
            const unsigned* dst = (const unsigned*)(h_out
                + ((size_t)((mb * 2 + s) * 16 + c_hi) << 9) + (gsub << 7)) + lane;
            asm volatile("global_store_dword %0, %1, off sc0 sc1" :: "v"(dst), "v"(vmain[s]));
        }
        if (h_aux)
#pragma unroll
            for (int s = 0; s < 2; ++s) {
                const unsigned* dst = (const unsigned*)(h_aux
                    + ((size_t)((mb * 2 + s) * 16 + c_hi) << 9) + (gsub << 7)) + lane;
                asm volatile("global_store_dword %0, %1, off sc0 sc1" :: "v"(dst), "v"(vaux[s]));
            }
    }
}

// ---------------- persistent kernel: grid 128, 64-wide n' waves ----------------
// FRESH=1: unique address per timestep -> readers use L2-cached loads.
// FRESH=0: r11 double-buffer + sc loads (fallback when ws too small).

template<int FRESH>
__global__ void __launch_bounds__(512, 1) persist_kernel(
    const short* __restrict__ X2t,
    const short* __restrict__ W0, const short* __restrict__ W1,
    const short* __restrict__ Wd1, const short* __restrict__ Wd2,
    short* hA, short* hd, short* hB,          // FRESH: history bases; else: buf0
    short* hA1, short* hd1, short* hB1,       // fallback bufs
    short* decA, short* hBall0, short* hBallR,
    const float* __restrict__ bias0, const float* __restrict__ bias1,
    const float* __restrict__ biasd1, const float* __restrict__ biasd2,
    const float* __restrict__ enc_mask, const float* __restrict__ dec_h_mask,
    const float* __restrict__ dec_c_mask, unsigned* bar)
{
    extern __shared__ __align__(16) char lds[];
    const int bid = blockIdx.x;
    const int xcd = bid & 7;
    const int half = xcd >> 2;
    const int m0 = ((xcd >> 1) & 1) * 256;
    const int ntile = ((bid >> 3) << 1) | (xcd & 1);   // 0..31
    const int np0 = ntile * 64;
    const int u0 = np0 >> 2;
    const int w = threadIdx.x >> 6;
    const int mb = (m0 >> 5) + ((w >> 2) << 2) + (w & 3);  // = (m0>>5)+w
    const int mrow = m0 + (w << 5);
    char* scrw = lds + 131072 + (w << 12);
    float creg[2][4] = {{0.f,0.f,0.f,0.f},{0.f,0.f,0.f,0.f}};

    auto hA_rd = [&](int t) -> const short* { return FRESH ? hA + (size_t)t * SL : ((t & 1) ? hA1 : hA); };
    auto hA_wr = [&](int t) -> short* { return FRESH ? hA + (size_t)(t + 1) * SL : ((t & 1) ? hA : hA1); };
    auto hd_at = [&](int t) -> short* { return FRESH ? hd + (size_t)t * SL : ((t & 1) ? hd1 : hd); };
    auto hB_rd = [&](int t) -> const short* { return FRESH ? hB + (size_t)t * SL : ((t & 1) ? hB1 : hB); };
    auto hB_wr = [&](int t) -> short* { return FRESH ? hB + (size_t)(t + 1) * SL : ((t & 1) ? hB : hB1); };
    auto decA_at = [&](int i) -> short* {
        if (FRESH) return (i == 0) ? hA + (size_t)128 * SL : decA + (size_t)(i - 1) * SL;
        return (i & 1) ? hA1 : hA;
    };
    auto hball = [&](int i) -> short* { return (i == 0) ? hBall0 : hBallR + (size_t)(i - 1) * SL; };

    // ---- encoder ----
    load_wres64(lds, (half ? W1 : W0) + (size_t)np0 * (half ? 1024 : 640), half ? 1024 : 640);
    __syncthreads();
    unsigned ep = 0;
    for (int tt = 0; tt <= TST; ++tt) {
        if (half == 0) {
            if (tt < TST) {
                const int t = tt;
                float ma[8];
                pre_mask_asm(enc_mask + (size_t)t * SBZ, mrow, u0, ma);
                pre_mask_asm(enc_mask + (size_t)t * SBZ, mrow, u0 + 8, ma + 4);
                f32x4 acc[2][4];
#pragma unroll
                for (int a = 0; a < 2; ++a)
#pragma unroll
                    for (int b2 = 0; b2 < 4; ++b2) acc[a][b2] = (f32x4){0.f, 0.f, 0.f, 0.f};
                gemm64<4, 16, !FRESH>(lds, X2t + (size_t)t * 65536, hA_rd(t), mb, acc);
                cell_epi64(scrw, acc, creg, mb, np0, bias0, nullptr, nullptr, ma,
                           hA_wr(t), hd_at(t));
            }
        } else {
            if (tt >= 1) {
                const int t = tt - 1;
                f32x4 acc[2][4];
#pragma unroll
                for (int a = 0; a < 2; ++a)
#pragma unroll
                    for (int b2 = 0; b2 < 4; ++b2) acc[a][b2] = (f32x4){0.f, 0.f, 0.f, 0.f};
                gemm64<16, 16, !FRESH>(lds, hd_at(t), hB_rd(t), mb, acc);
                short* outp = (t == TST - 1) ? hBall0 : hB_wr(t);
                cell_epi64(scrw, acc, creg, mb, np0, bias1, nullptr, nullptr, nullptr,
                           outp, nullptr);
            }
        }
        gbar(bar, bid, ++ep);
    }

    // ---- decoder ----
    load_wres64(lds, (half ? Wd2 : Wd1) + (size_t)np0 * 1024, 1024);
    __syncthreads();
    for (int s = 0; s < HOR - 1; ++s) {
        if (half == 0) {
            float mh[8], mc[8];
            pre_mask_asm(dec_h_mask + (size_t)s * SBZ, mrow, u0, mh);
            pre_mask_asm(dec_h_mask + (size_t)s * SBZ, mrow, u0 + 8, mh + 4);
            pre_mask_asm(dec_c_mask + (size_t)s * SBZ, mrow, u0, mc);
            pre_mask_asm(dec_c_mask + (size_t)s * SBZ, mrow, u0 + 8, mc + 4);
            f32x4 acc[2][4];
#pragma unroll
            for (int a = 0; a < 2; ++a)
#pragma unroll
                for (int b2 = 0; b2 < 4; ++b2) acc[a][b2] = (f32x4){0.f, 0.f, 0.f, 0.f};
            gemm64<16, 16, !FRESH>(lds, hball(s), decA_at(s), mb, acc);
            cell_epi64(scrw, acc, creg, mb, np0, biasd1, mh, mc, nullptr,
                       decA_at(s + 1), nullptr);
        }
        gbar(bar, bid, ++ep);
        if (half == 1) {
            f32x4 acc[2][4];
#pragma unroll
            for (int a = 0; a < 2; ++a)
#pragma unroll
                for (int b2 = 0; b2 < 4; ++b2) acc[a][b2] = (f32x4){0.f, 0.f, 0.f, 0.f};
            gemm64<16, 16, !FRESH>(lds, decA_at(s + 1), hball(s), mb, acc);
            cell_epi64(scrw, acc, creg, mb, np0, biasd2, nullptr, nullptr, nullptr,
                       hball(s + 1), nullptr);
        }
        gbar(bar, bid, ++ep);
    }
}

// ---------------- batched projection (r11-verified, 32-row path) ----------------

template<int C0, int C1>
__device__ __forceinline__ void gemm_pipeP(
    const char* wres, const short* a0t, const short* a1t,
    int mb, f32x4 acc[2][2])
{
    constexpr int NKC = C0 + C1;
    constexpr int D = 16;
    const int lane = threadIdx.x & 63;
    const int arow = lane & 15, akg = lane >> 4;
    const size_t lb = (size_t)lane << 4;
    const char* base0 = (const char*)a0t;
    const char* base1 = (const char*)a1t;
    auto cptr = [&](int kc, int fh) -> const char* {
        return (kc < C0)
            ? base0 + (((size_t)(mb * 2 + fh) * C0 + kc) << 10) + lb
            : base1 + (((size_t)(mb * 2 + fh) * C1 + (kc - C0)) << 10) + lb;
    };
    f32x4 q0[D], q1[D];
#pragma unroll
    for (int i = 0; i < D; ++i) {
        gl16<true>(q0[i], cptr(i, 0));
        gl16<true>(q1[i], cptr(i, 1));
    }
#pragma unroll
    for (int kc = 0; kc < NKC; ++kc) {
        const int sl = kc % D;
        asm volatile("s_waitcnt vmcnt(%2)"
                     : "+v"(q0[sl]), "+v"(q1[sl])
                     : "i"((2 * ((NKC - kc) < D ? (NKC - kc) : D)) - 2));
        const bf16x8 fa0 = asbf(q0[sl]);
        const bf16x8 fa1 = asbf(q1[sl]);
        if (kc + D < NKC) {
            gl16<true>(q0[sl], cptr(kc + D, 0));
            gl16<true>(q1[sl], cptr(kc + D, 1));
        }
        const char* wrow = wres + (size_t)(((kc << 2) + akg) << 9);
        const bf16x8 fb0 = *(const bf16x8*)(wrow + (arow << 4));
        const bf16x8 fb1 = *(const bf16x8*)(wrow + ((16 + arow) << 4));
        acc[0][0] = __builtin_amdgcn_mfma_f32_16x16x32_bf16(fa0, fb0, acc[0][0], 0, 0, 0);
        acc[0][1] = __builtin_amdgcn_mfma_f32_16x16x32_bf16(fa0, fb1, acc[0][1], 0, 0, 0);
        acc[1][0] = __builtin_amdgcn_mfma_f32_16x16x32_bf16(fa1, fb0, acc[1][0], 0, 0, 0);
        acc[1][1] = __builtin_amdgcn_mfma_f32_16x16x32_bf16(fa1, fb1, acc[1][1], 0, 0, 0);
    }
    asm volatile("s_waitcnt vmcnt(0)");
}

__global__ void __launch_bounds__(512, 2) proj_kernel(
    const short* hBall0, const short* hBallR, const short* __restrict__ W2p,
    const float* __restrict__ bp, float* __restrict__ pred_all)
{
    extern __shared__ __align__(16) char lds[];
    const int bid = blockIdx.x;
    const int s = bid >> 3, q = bid & 7;
    const int bh = q >> 2, n0p = (q & 3) * 32;
    load_wres32(lds, W2p + (size_t)n0p * 512, 512);
    const int w = threadIdx.x >> 6, lane = threadIdx.x & 63;
    char* scrw = lds + 32768 + w * 4608;
    const int mb = bh * 8 + w;
    const short* A = (s == 0) ? hBall0 : hBallR + (size_t)(s - 1) * SL;
    __syncthreads();
    f32x4 acc[2][2];
#pragma unroll
    for (int a = 0; a < 2; ++a)
#pragma unroll
        for (int b2 = 0; b2 < 2; ++b2) acc[a][b2] = (f32x4){0.f, 0.f, 0.f, 0.f};
    gemm_pipeP<16, 0>(lds, A, A, mb, acc);
#pragma unroll
    for (int mi = 0; mi < 2; ++mi)
#pragma unroll
        for (int ni = 0; ni < 2; ++ni) {
            const int row = mi * 16 + ((lane >> 4) << 2);
            const int col = ni * 16 + (lane & 15);
#pragma unroll
            for (int r = 0; r < 4; ++r)
                *(float*)(scrw + (row + r) * 144 + (col << 2)) = acc[mi][ni][r];
        }
    asm volatile("s_waitcnt lgkmcnt(0)" ::: "memory");
    const int rr = lane >> 1, hf = lane & 1;
    float* dst = pred_all + (size_t)s * (BAT * NIN)
               + (size_t)(bh * 256 + w * 32 + rr) * NIN + n0p + hf * 16;
#pragma unroll
    for (int t4 = 0; t4 < 4; ++t4) {
        f32x4 v = *(const f32x4*)(scrw + rr * 144 + hf * 64 + t4 * 16);
        const float4 b4 = *(const float4*)(bp + n0p + hf * 16 + t4 * 4);
        v[0] += b4.x; v[1] += b4.y; v[2] += b4.z; v[3] += b4.w;
        *(f32x4*)(dst + t4 * 4) = v;
    }
}

__global__ __launch_bounds__(256) void transpose_out(const float* __restrict__ pred_all,
                                                     float* __restrict__ out) {
    __shared__ float tl[32][65];
    const int base = blockIdx.x * 64;
    const int tid = threadIdx.x;
    for (int i = tid; i < 32 * 64; i += 256) {
        int s = i >> 6, f = i & 63;
        tl[s][f] = pred_all[(size_t)s * (BAT * NIN) + base + f];
    }
    __syncthreads();
    for (int i = tid; i < 64 * 32; i += 256) {
        int f = i >> 5, s = i & 31;
        out[(size_t)(base + f) * HOR + s] = tl[s][f];
    }
}

// ---------------- host ----------------

extern "C" void kernel_launch(void* const* d_in, const int* in_sizes, int n_in,
                              void* d_out, int out_size, void* d_ws, size_t ws_size,
                              hipStream_t stream) {
    (void)in_sizes; (void)n_in; (void)out_size;
    const float* window = (const float*)d_in[0];
    const float* Wih0 = (const float*)d_in[1];
    const float* Whh0 = (const float*)d_in[2];
    const float* bih0 = (const float*)d_in[3];
    const float* bhh0 = (const float*)d_in[4];
    const float* Wih1 = (const float*)d_in[5];
    const float* Whh1 = (const float*)d_in[6];
    const float* bih1 = (const float*)d_in[7];
    const float* bhh1 = (const float*)d_in[8];
    const float* Wc1i = (const float*)d_in[9];
    const float* Wc1h = (const float*)d_in[10];
    const float* bc1i = (const float*)d_in[11];
    const float* bc1h = (const float*)d_in[12];
    const float* Wc2i = (const float*)d_in[13];
    const float* Wc2h = (const float*)d_in[14];
    const float* bc2i = (const float*)d_in[15];
    const float* bc2h = (const float*)d_in[16];
    const float* Wp   = (const float*)d_in[17];
    const float* bp   = (const float*)d_in[18];
    const float* enc_mask   = (const float*)d_in[19];
    const float* dec_h_mask = (const float*)d_in[20];
    const float* dec_c_mask = (const float*)d_in[21];
    float* out = (float*)d_out;

    char* base = (char*)d_ws;
    size_t off = 0;
    auto take = [&](size_t bytes) -> char* {
        off = (off + 255) & ~(size_t)255;
        char* r = base + off; off += bytes; return r;
    };
    short* W2e0 = (short*)take((size_t)2048 * 640 * 2);
    short* W2e1 = (short*)take((size_t)2048 * 1024 * 2);
    short* W2d1 = (short*)take((size_t)2048 * 1024 * 2);
    short* W2d2 = (short*)take((size_t)2048 * 1024 * 2);
    short* W2p  = (short*)take((size_t)128 * 512 * 2);
    float* Wfuse = (float*)take((size_t)2048 * 512 * 4);
    float* badd  = (float*)take((size_t)2048 * 4);
    float* bias0 = (float*)take((size_t)2048 * 4);
    float* bias1 = (float*)take((size_t)2048 * 4);
    float* biasd1 = (float*)take((size_t)2048 * 4);
    float* biasd2 = (float*)take((size_t)2048 * 4);
    short* hBall0 = (short*)take(SLB);
    float* pred_all = (float*)take((size_t)HOR * BAT * NIN * 4);
    unsigned* bars = (unsigned*)take(16384);
    short* X2t = (short*)take((size_t)TST * 65536 * 2);

    // FRESH histories: hA 129 + hd 128 + hB 129 + decA 31 + hballR 31 = 448 slots
    const size_t fresh_need = (size_t)448 * SLB + 65536;
    bool FRESHM = (ws_size >= off + fresh_need);
    short *hAp, *hdp, *hBp, *hA1p = nullptr, *hd1p = nullptr, *hB1p = nullptr;
    short *decAp = nullptr, *hballRp;
    if (FRESHM) {
        hAp    = (short*)take((size_t)129 * SLB);
        hdp    = (short*)take((size_t)128 * SLB);
        hBp    = (short*)take((size_t)129 * SLB);
        decAp  = (short*)take((size_t)31 * SLB);
        hballRp = (short*)take((size_t)31 * SLB);
    } else {
        hAp  = (short*)take(SLB); hA1p = (short*)take(SLB);
        hdp  = (short*)take(SLB); hd1p = (short*)take(SLB);
        hBp  = (short*)take(SLB); hB1p = (short*)take(SLB);
        hballRp = X2t;   // decoder h-history overlaps dead X2 region (r11-verified)
    }

    // prep (re-done every call; deterministic)
    prep_fuse<<<(2048 * 512 + 255) / 256, 256, 0, stream>>>(Wc1i, Wp, Wfuse);
    prep_badd<<<8, 256, 0, stream>>>(Wc1i, bp, badd);
    prep_wp<<<(128 * 512 + 255) / 256, 256, 0, stream>>>(Wp, W2p);
    prep_w<<<(2048 * 640 + 255) / 256, 256, 0, stream>>>(Wih0, Whh0, W2e0, NIN, 640);
    prep_w<<<(2048 * 1024 + 255) / 256, 256, 0, stream>>>(Wih1, Whh1, W2e1, HID, 1024);
    prep_w<<<(2048 * 1024 + 255) / 256, 256, 0, stream>>>(Wfuse, Wc1h, W2d1, HID, 1024);
    prep_w<<<(2048 * 1024 + 255) / 256, 256, 0, stream>>>(Wc2i, Wc2h, W2d2, HID, 1024);
    prep_bias<<<8, 256, 0, stream>>>(bih0, bhh0, nullptr, bias0);
    prep_bias<<<8, 256, 0, stream>>>(bih1, bhh1, nullptr, bias1);
    prep_bias<<<8, 256, 0, stream>>>(bc1i, bc1h, badd, biasd1);
    prep_bias<<<8, 256, 0, stream>>>(bc2i, bc2h, nullptr, biasd2);
    prep_x<<<(int)(((size_t)TST * BAT * NIN + 255) / 256), 256, 0, stream>>>(window, X2t);
    hipMemsetAsync(hAp, 0, SLB, stream);        // hA slot0 / hA0
    hipMemsetAsync(hBp, 0, SLB, stream);        // hB slot0 / hB0
    hipMemsetAsync(bars, 0, 16384, stream);

    if (FRESHM) {
        hipFuncSetAttribute((const void*)&persist_kernel<1>,
                            hipFuncAttributeMaxDynamicSharedMemorySize, 163840);
        persist_kernel<1><<<128, 512, 163840, stream>>>(
            X2t, W2e0, W2e1, W2d1, W2d2,
            hAp, hdp, hBp, hA1p, hd1p, hB1p,
            decAp, hBall0, hballRp,
            bias0, bias1, biasd1, biasd2,
            enc_mask, dec_h_mask, dec_c_mask, bars);
    } else {
        hipFuncSetAttribute((const void*)&persist_kernel<0>,
                            hipFuncAttributeMaxDynamicSharedMemorySize, 163840);
        persist_kernel<0><<<128, 512, 163840, stream>>>(
            X2t, W2e0, W2e1, W2d1, W2d2,
            hAp, hdp, hBp, hA1p, hd1p, hB1p,
            decAp, hBall0, hballRp,
            bias0, bias1, biasd1, biasd2,
            enc_mask, dec_h_mask, dec_c_mask, bars);
    }

    hipFuncSetAttribute((const void*)&proj_kernel,
                        hipFuncAttributeMaxDynamicSharedMemorySize, 69632);
    proj_kernel<<<256, 512, 69632, stream>>>(hBall0, hballRp, W2p, bp, pred_all);

    transpose_out<<<(BAT * NIN) / 64, 256, 0, stream>>>(pred_all, out);
}

// Round 13
// 1788.309 us; speedup vs baseline: 1.2819x; 1.2819x over previous
//
#include <hip/hip_runtime.h>
#include <math.h>

#define HID 512
#define BAT 512
#define NIN 128
#define TST 128
#define HOR 32
#define SBZ ((size_t)BAT * HID)
#define SL 262144            // shorts per h-slot (512x512 bf16)
#define SLB 524288           // bytes per h-slot

using bf16x8 = __attribute__((ext_vector_type(8))) __bf16;
using f32x4  = __attribute__((ext_vector_type(4))) float;

__device__ __forceinline__ float sigf(float x) { return 1.0f / (1.0f + __expf(-x)); }
__device__ __forceinline__ float tanhfast(float x) { return 1.0f - 2.0f / (__expf(2.0f * x) + 1.0f); }

__device__ __forceinline__ short f2bf(float x) {
    union { float f; unsigned u; } v; v.f = x;
    unsigned r = (v.u + 0x7FFFu + ((v.u >> 16) & 1u)) >> 16;
    return (short)r;
}
__device__ __forceinline__ float bf2f(short s) {
    union { unsigned u; float f; } v; v.u = ((unsigned)(unsigned short)s) << 16;
    return v.f;
}
__device__ __forceinline__ bf16x8 asbf(f32x4 v) {
    union { f32x4 f; bf16x8 b; } u; u.f = v; return u.b;
}

// Fence-free hierarchical grid barrier for 256 blocks (32 leaves x 8). r10/r11-verified.
__device__ __forceinline__ void gbar3(unsigned* bar, int bid, unsigned ep) {
    __syncthreads();
    if (threadIdx.x == 0) {
        unsigned* leaf = bar + ((unsigned)bid >> 3) * 32;
        unsigned* root = bar + 1024;
        unsigned* flag = bar + 1056;
        unsigned old = __hip_atomic_fetch_add(leaf, 1u, __ATOMIC_RELAXED, __HIP_MEMORY_SCOPE_AGENT);
        if (old == 8u * ep - 1u) {
            unsigned ro = __hip_atomic_fetch_add(root, 1u, __ATOMIC_RELAXED, __HIP_MEMORY_SCOPE_AGENT);
            if (ro == 32u * ep - 1u)
                __hip_atomic_store(flag, ep, __ATOMIC_RELAXED, __HIP_MEMORY_SCOPE_AGENT);
        }
        int spin = 0;
        while (__hip_atomic_load(flag, __ATOMIC_RELAXED, __HIP_MEMORY_SCOPE_AGENT) < ep) {
            __builtin_amdgcn_s_sleep(1);
            if (((++spin) & 63) == 0)
                __hip_atomic_fetch_add(flag, 0u, __ATOMIC_RELAXED, __HIP_MEMORY_SCOPE_AGENT);
        }
    }
    __syncthreads();
}

// ---------------- prep kernels (r11-verified) ----------------

__global__ __launch_bounds__(256) void prep_w(const float* __restrict__ Wih,
                                              const float* __restrict__ Whh,
                                              short* __restrict__ W2, int Kx, int Kp) {
    size_t i = (size_t)blockIdx.x * 256 + threadIdx.x;
    if (i >= (size_t)2048 * Kp) return;
    int np = (int)(i / Kp), kp = (int)(i % Kp);
    int u = np >> 2, gate = np & 3;
    int on = gate * HID + u;
    float w = (kp < Kx) ? Wih[(size_t)on * Kx + kp] : Whh[(size_t)on * HID + (kp - Kx)];
    W2[i] = f2bf(w);
}

__global__ __launch_bounds__(256) void prep_x(const float* __restrict__ window,
                                              short* __restrict__ X2t) {
    size_t i = (size_t)blockIdx.x * 256 + threadIdx.x;
    if (i >= (size_t)TST * BAT * NIN) return;
    int n = (int)(i & 127);
    int b = (int)((i >> 7) & 511);
    int t = (int)(i >> 16);
    float x = window[(size_t)b * (TST * NIN) + (size_t)t * NIN + n];
    int rg = b >> 4;
    int l = (b & 15) + (((n >> 3) & 3) << 4);
    int e = n & 7;
    size_t base = (size_t)t * 65536 + ((size_t)(rg * 4 + (n >> 5)) << 9) + l * 8 + e;
    X2t[base] = f2bf(x);
}

__global__ __launch_bounds__(256) void prep_fuse(const float* __restrict__ Wc1i,
                                                 const float* __restrict__ Wp,
                                                 float* __restrict__ Wfuse) {
    size_t i = (size_t)blockIdx.x * 256 + threadIdx.x;
    if (i >= (size_t)2048 * 512) return;
    int on = (int)(i >> 9), k = (int)(i & 511);
    float s = 0.f;
    for (int n = 0; n < NIN; ++n) s += Wc1i[(size_t)on * NIN + n] * Wp[(size_t)n * HID + k];
    Wfuse[i] = s;
}

__global__ __launch_bounds__(256) void prep_badd(const float* __restrict__ Wc1i,
                                                 const float* __restrict__ bp,
                                                 float* __restrict__ badd) {
    int on = blockIdx.x * 256 + threadIdx.x;
    if (on >= 2048) return;
    float s = 0.f;
    for (int n = 0; n < NIN; ++n) s += Wc1i[(size_t)on * NIN + n] * bp[n];
    badd[on] = s;
}

__global__ __launch_bounds__(256) void prep_bias(const float* __restrict__ bih,
                                                 const float* __restrict__ bhh,
                                                 const float* __restrict__ badd,
                                                 float* __restrict__ bout) {
    int np = blockIdx.x * 256 + threadIdx.x;
    if (np >= 2048) return;
    int on = (np & 3) * HID + (np >> 2);
    float v = bih[on] + bhh[on];
    if (badd) v += badd[on];
    bout[np] = v;
}

__global__ __launch_bounds__(256) void prep_wp(const float* __restrict__ Wp,
                                               short* __restrict__ W2p) {
    int i = blockIdx.x * 256 + threadIdx.x;
    if (i >= 128 * 512) return;
    W2p[i] = f2bf(Wp[i]);
}

// ---------------- device building blocks ----------------

__device__ __forceinline__ void gl16sc(f32x4& q, const char* p) {
    asm volatile("global_load_dwordx4 %0, %1, off sc0 sc1" : "=v"(q) : "v"(p));
}

// 32-row resident W (proj): lds[j*512 + r*16]
__device__ __forceinline__ void load_wres32(char* lds, const short* Wg, int K) {
    const int tid = threadIdx.x;
    const int r = tid >> 4;
    const int cnt = K >> 7;
    const int jb = (tid & 15) * cnt;
    for (int q = 0; q < cnt; ++q) {
        int j = jb + q;
        bf16x8 v = *(const bf16x8*)(Wg + (size_t)r * K + j * 8);
        *(bf16x8*)(lds + j * 512 + r * 16) = v;
    }
}

// 64-row resident W (persist, 256 threads): lds[j*1024 + r*16], r=0..63
__device__ __forceinline__ void load_wres64(char* lds, const short* Wg, int K) {
    const int r = threadIdx.x >> 2, jg = threadIdx.x & 3;
    for (int q = 0; q < (K >> 5); ++q) {
        int j = jg + (q << 2);
        bf16x8 v = *(const bf16x8*)(Wg + (size_t)r * K + j * 8);
        *(bf16x8*)(lds + (size_t)j * 1024 + r * 16) = v;
    }
}

// mask prefetch (asm loads BEFORE counted loads: oldest-first drain keeps vmcnt math safe)
__device__ __forceinline__ void pre_mask_asm(const float* msk, int mrow, int u0, float o[4]) {
    const int lane = threadIdx.x & 63;
    const float* p = msk + (size_t)(mrow + ((lane >> 3) << 2)) * HID + u0 + (lane & 7);
#pragma unroll
    for (int r = 0; r < 4; ++r)
        asm volatile("global_load_dword %0, %1, off" : "=v"(o[r]) : "v"(p + (size_t)r * HID));
}

// Wave GEMM 32(m) x 64(n') over chunked A (1KB contiguous loads, sc0sc1);
// counted-vmcnt depth D=16; W from 64-row resident LDS. (r12-verified body, D up.)
template<int C0, int C1>
__device__ __forceinline__ void gemm64(
    const char* wres, const short* a0t, const short* a1t,
    int mb, f32x4 acc[2][4])
{
    constexpr int NKC = C0 + C1;
    constexpr int D = 16;
    const int lane = threadIdx.x & 63;
    const int arow = lane & 15, akg = lane >> 4;
    const size_t lb = (size_t)lane << 4;
    const char* base0 = (const char*)a0t;
    const char* base1 = (const char*)a1t;
    auto cptr = [&](int kc, int fh) -> const char* {
        return (kc < C0)
            ? base0 + (((size_t)(mb * 2 + fh) * C0 + kc) << 10) + lb
            : base1 + (((size_t)(mb * 2 + fh) * C1 + (kc - C0)) << 10) + lb;
    };
    f32x4 q0[D], q1[D];
#pragma unroll
    for (int i = 0; i < D; ++i) {
        gl16sc(q0[i], cptr(i, 0));
        gl16sc(q1[i], cptr(i, 1));
    }
#pragma unroll
    for (int kc = 0; kc < NKC; ++kc) {
        const int sl = kc % D;
        asm volatile("s_waitcnt vmcnt(%2)"
                     : "+v"(q0[sl]), "+v"(q1[sl])
                     : "i"((2 * ((NKC - kc) < D ? (NKC - kc) : D)) - 2));
        const bf16x8 fa0 = asbf(q0[sl]);
        const bf16x8 fa1 = asbf(q1[sl]);
        if (kc + D < NKC) {
            gl16sc(q0[sl], cptr(kc + D, 0));
            gl16sc(q1[sl], cptr(kc + D, 1));
        }
        const char* wrow = wres + (size_t)((kc << 2) + akg) * 1024;
        bf16x8 fb[4];
#pragma unroll
        for (int nj = 0; nj < 4; ++nj)
            fb[nj] = *(const bf16x8*)(wrow + ((nj * 16 + arow) << 4));
#pragma unroll
        for (int nj = 0; nj < 4; ++nj) {
            acc[0][nj] = __builtin_amdgcn_mfma_f32_16x16x32_bf16(fa0, fb[nj], acc[0][nj], 0, 0, 0);
            acc[1][nj] = __builtin_amdgcn_mfma_f32_16x16x32_bf16(fa1, fb[nj], acc[1][nj], 0, 0, 0);
        }
    }
    asm volatile("s_waitcnt vmcnt(0)");
}

// Wave LSTM epilogue over 32 rows x 64 n' in two 32-wide passes (r12-verified).
__device__ __forceinline__ void cell_epi64(
    char* scrw, f32x4 acc[2][4], float creg[2][4], int mb, int np0,
    const float* bias_p, const float* mh, const float* mc, const float* ma,
    short* h_out, short* h_aux)
{
    const int lane = threadIdx.x & 63;
#pragma unroll
    for (int p = 0; p < 2; ++p) {
        const int np0p = np0 + (p << 5);
#pragma unroll
        for (int mi = 0; mi < 2; ++mi)
#pragma unroll
            for (int nj = 0; nj < 2; ++nj) {
                const int row = mi * 16 + ((lane >> 4) << 2);
                const int col = nj * 16 + (lane & 15);
#pragma unroll
                for (int r = 0; r < 4; ++r)
                    *(float*)(scrw + (row + r) * 128 + (col << 2)) = acc[mi][p * 2 + nj][r];
            }
        asm volatile("s_waitcnt lgkmcnt(0)" ::: "memory");
        const int ul = lane & 7, g = lane >> 3;
        f32x4 gv[4];
#pragma unroll
        for (int r = 0; r < 4; ++r)
            gv[r] = *(const f32x4*)(scrw + ((g << 2) + r) * 128 + (ul << 4));
        asm volatile("s_waitcnt lgkmcnt(0)" ::: "memory");
        const float4 bs = *(const float4*)(bias_p + np0p + (ul << 2));
#pragma unroll
        for (int r = 0; r < 4; ++r) {
            const int m = (g << 2) + r;
            const int fh = m >> 4, r16 = m & 15;
            const float gi = gv[r][0] + bs.x, gf = gv[r][1] + bs.y;
            const float gg = gv[r][2] + bs.z, go = gv[r][3] + bs.w;
            const float cn = sigf(gf) * creg[p][r] + sigf(gi) * tanhfast(gg);
            const float h  = sigf(go) * tanhfast(cn);
            creg[p][r] = mc ? cn * mc[p * 4 + r] : cn;
            const float hm = mh ? h * mh[p * 4 + r] : h;
            const int idx2 = (r16 << 3) + ul;
            *(short*)(scrw + fh * 256 + idx2 * 2) = f2bf(hm);
            if (h_aux)
                *(short*)(scrw + 512 + fh * 256 + idx2 * 2) = f2bf(h * ma[p * 4 + r]);
        }
        const int u0p = np0p >> 2;
        const int c_hi = u0p >> 5, gsub = (u0p >> 3) & 3;
        unsigned vmain[2], vaux[2];
#pragma unroll
        for (int s = 0; s < 2; ++s)
            vmain[s] = *(const unsigned*)(scrw + s * 256 + (lane << 2));
        if (h_aux)
#pragma unroll
            for (int s = 0; s < 2; ++s)
                vaux[s] = *(const unsigned*)(scrw + 512 + s * 256 + (lane << 2));
        asm volatile("s_waitcnt lgkmcnt(0)" ::: "memory");
#pragma unroll
        for (int s = 0; s < 2; ++s) {
            const unsigned* dst = (const unsigned*)(h_out
                + ((size_t)((mb * 2 + s) * 16 + c_hi) << 9) + (gsub << 7)) + lane;
            asm volatile("global_store_dword %0, %1, off sc0 sc1" :: "v"(dst), "v"(vmain[s]));
        }
        if (h_aux)
#pragma unroll
            for (int s = 0; s < 2; ++s) {
                const unsigned* dst = (const unsigned*)(h_aux
                    + ((size_t)((mb * 2 + s) * 16 + c_hi) << 9) + (gsub << 7)) + lane;
                asm volatile("global_store_dword %0, %1, off sc0 sc1" :: "v"(dst), "v"(vaux[s]));
            }
    }
}

// ---------------- persistent kernel: grid 256 x 256thr, 64-wide n' waves ----------------
// Role map: xcd=bid&7: half = xcd>>2, mtile = xcd&3 (m0 = mtile*128, XCD-clustered rows),
// ntile = bid>>3 (np0 = ntile*64). 4 waves x 32 rows cover the 128-row mtile.

__global__ void __launch_bounds__(256, 1) persist_kernel(
    const short* __restrict__ X2t,
    const short* __restrict__ W0, const short* __restrict__ W1,
    const short* __restrict__ Wd1, const short* __restrict__ Wd2,
    short* hA0, short* hA1, short* hd0, short* hd1, short* hB0, short* hB1,
    short* hBall0, short* hBallR,
    const float* __restrict__ bias0, const float* __restrict__ bias1,
    const float* __restrict__ biasd1, const float* __restrict__ biasd2,
    const float* __restrict__ enc_mask, const float* __restrict__ dec_h_mask,
    const float* __restrict__ dec_c_mask, unsigned* bar)
{
    extern __shared__ __align__(16) char lds[];
    const int bid = blockIdx.x;
    const int xcd = bid & 7;
    const int half = xcd >> 2;
    const int m0 = (xcd & 3) * 128;
    const int ntile = bid >> 3;                 // 0..31
    const int np0 = ntile * 64;
    const int u0 = np0 >> 2;
    const int w = threadIdx.x >> 6;             // 0..3
    const int mb = (m0 >> 5) + w;
    const int mrow = m0 + (w << 5);
    char* scrw = lds + 131072 + (w << 12);
    float creg[2][4] = {{0.f,0.f,0.f,0.f},{0.f,0.f,0.f,0.f}};

    auto hA_rd = [&](int t) -> const short* { return (t & 1) ? hA1 : hA0; };
    auto hA_wr = [&](int t) -> short* { return (t & 1) ? hA0 : hA1; };
    auto hd_at = [&](int t) -> short* { return (t & 1) ? hd1 : hd0; };
    auto hB_rd = [&](int t) -> const short* { return (t & 1) ? hB1 : hB0; };
    auto hB_wr = [&](int t) -> short* { return (t & 1) ? hB0 : hB1; };
    auto decA_at = [&](int i) -> short* { return (i & 1) ? hA1 : hA0; };
    auto hball = [&](int i) -> short* { return (i == 0) ? hBall0 : hBallR + (size_t)(i - 1) * SL; };

    // ---- encoder ----
    load_wres64(lds, (half ? W1 : W0) + (size_t)np0 * (half ? 1024 : 640), half ? 1024 : 640);
    __syncthreads();
    unsigned ep = 0;
    for (int tt = 0; tt <= TST; ++tt) {
        if (half == 0) {
            if (tt < TST) {
                const int t = tt;
                float ma[8];
                pre_mask_asm(enc_mask + (size_t)t * SBZ, mrow, u0, ma);
                pre_mask_asm(enc_mask + (size_t)t * SBZ, mrow, u0 + 8, ma + 4);
                f32x4 acc[2][4];
#pragma unroll
                for (int a = 0; a < 2; ++a)
#pragma unroll
                    for (int b2 = 0; b2 < 4; ++b2) acc[a][b2] = (f32x4){0.f, 0.f, 0.f, 0.f};
                gemm64<4, 16>(lds, X2t + (size_t)t * 65536, hA_rd(t), mb, acc);
                cell_epi64(scrw, acc, creg, mb, np0, bias0, nullptr, nullptr, ma,
                           hA_wr(t), hd_at(t));
            }
        } else {
            if (tt >= 1) {
                const int t = tt - 1;
                f32x4 acc[2][4];
#pragma unroll
                for (int a = 0; a < 2; ++a)
#pragma unroll
                    for (int b2 = 0; b2 < 4; ++b2) acc[a][b2] = (f32x4){0.f, 0.f, 0.f, 0.f};
                gemm64<16, 16>(lds, hd_at(t), hB_rd(t), mb, acc);
                short* outp = (t == TST - 1) ? hBall0 : hB_wr(t);
                cell_epi64(scrw, acc, creg, mb, np0, bias1, nullptr, nullptr, nullptr,
                           outp, nullptr);
            }
        }
        gbar3(bar, bid, ++ep);
    }

    // ---- decoder ----
    load_wres64(lds, (half ? Wd2 : Wd1) + (size_t)np0 * 1024, 1024);
    __syncthreads();
    for (int s = 0; s < HOR - 1; ++s) {
        if (half == 0) {
            float mh[8], mc[8];
            pre_mask_asm(dec_h_mask + (size_t)s * SBZ, mrow, u0, mh);
            pre_mask_asm(dec_h_mask + (size_t)s * SBZ, mrow, u0 + 8, mh + 4);
            pre_mask_asm(dec_c_mask + (size_t)s * SBZ, mrow, u0, mc);
            pre_mask_asm(dec_c_mask + (size_t)s * SBZ, mrow, u0 + 8, mc + 4);
            f32x4 acc[2][4];
#pragma unroll
            for (int a = 0; a < 2; ++a)
#pragma unroll
                for (int b2 = 0; b2 < 4; ++b2) acc[a][b2] = (f32x4){0.f, 0.f, 0.f, 0.f};
            gemm64<16, 16>(lds, hball(s), decA_at(s), mb, acc);
            cell_epi64(scrw, acc, creg, mb, np0, biasd1, mh, mc, nullptr,
                       decA_at(s + 1), nullptr);
        }
        gbar3(bar, bid, ++ep);
        if (half == 1) {
            f32x4 acc[2][4];
#pragma unroll
            for (int a = 0; a < 2; ++a)
#pragma unroll
                for (int b2 = 0; b2 < 4; ++b2) acc[a][b2] = (f32x4){0.f, 0.f, 0.f, 0.f};
            gemm64<16, 16>(lds, decA_at(s + 1), hball(s), mb, acc);
            cell_epi64(scrw, acc, creg, mb, np0, biasd2, nullptr, nullptr, nullptr,
                       hball(s + 1), nullptr);
        }
        gbar3(bar, bid, ++ep);
    }
}

// ---------------- batched projection (r11-verified) ----------------

template<int C0, int C1>
__device__ __forceinline__ void gemm_pipeP(
    const char* wres, const short* a0t, const short* a1t,
    int mb, f32x4 acc[2][2])
{
    constexpr int NKC = C0 + C1;
    constexpr int D = 16;
    const int lane = threadIdx.x & 63;
    const int arow = lane & 15, akg = lane >> 4;
    const size_t lb = (size_t)lane << 4;
    const char* base0 = (const char*)a0t;
    const char* base1 = (const char*)a1t;
    auto cptr = [&](int kc, int fh) -> const char* {
        return (kc < C0)
            ? base0 + (((size_t)(mb * 2 + fh) * C0 + kc) << 10) + lb
            : base1 + (((size_t)(mb * 2 + fh) * C1 + (kc - C0)) << 10) + lb;
    };
    f32x4 q0[D], q1[D];
#pragma unroll
    for (int i = 0; i < D; ++i) {
        gl16sc(q0[i], cptr(i, 0));
        gl16sc(q1[i], cptr(i, 1));
    }
#pragma unroll
    for (int kc = 0; kc < NKC; ++kc) {
        const int sl = kc % D;
        asm volatile("s_waitcnt vmcnt(%2)"
                     : "+v"(q0[sl]), "+v"(q1[sl])
                     : "i"((2 * ((NKC - kc) < D ? (NKC - kc) : D)) - 2));
        const bf16x8 fa0 = asbf(q0[sl]);
        const bf16x8 fa1 = asbf(q1[sl]);
        if (kc + D < NKC) {
            gl16sc(q0[sl], cptr(kc + D, 0));
            gl16sc(q1[sl], cptr(kc + D, 1));
        }
        const char* wrow = wres + (size_t)(((kc << 2) + akg) << 9);
        const bf16x8 fb0 = *(const bf16x8*)(wrow + (arow << 4));
        const bf16x8 fb1 = *(const bf16x8*)(wrow + ((16 + arow) << 4));
        acc[0][0] = __builtin_amdgcn_mfma_f32_16x16x32_bf16(fa0, fb0, acc[0][0], 0, 0, 0);
        acc[0][1] = __builtin_amdgcn_mfma_f32_16x16x32_bf16(fa0, fb1, acc[0][1], 0, 0, 0);
        acc[1][0] = __builtin_amdgcn_mfma_f32_16x16x32_bf16(fa1, fb0, acc[1][0], 0, 0, 0);
        acc[1][1] = __builtin_amdgcn_mfma_f32_16x16x32_bf16(fa1, fb1, acc[1][1], 0, 0, 0);
    }
    asm volatile("s_waitcnt vmcnt(0)");
}

__global__ void __launch_bounds__(512, 2) proj_kernel(
    const short* hBall0, const short* hBallR, const short* __restrict__ W2p,
    const float* __restrict__ bp, float* __restrict__ pred_all)
{
    extern __shared__ __align__(16) char lds[];
    const int bid = blockIdx.x;
    const int s = bid >> 3, q = bid & 7;
    const int bh = q >> 2, n0p = (q & 3) * 32;
    load_wres32(lds, W2p + (size_t)n0p * 512, 512);
    const int w = threadIdx.x >> 6, lane = threadIdx.x & 63;
    char* scrw = lds + 32768 + w * 4608;
    const int mb = bh * 8 + w;
    const short* A = (s == 0) ? hBall0 : hBallR + (size_t)(s - 1) * SL;
    __syncthreads();
    f32x4 acc[2][2];
#pragma unroll
    for (int a = 0; a < 2; ++a)
#pragma unroll
        for (int b2 = 0; b2 < 2; ++b2) acc[a][b2] = (f32x4){0.f, 0.f, 0.f, 0.f};
    gemm_pipeP<16, 0>(lds, A, A, mb, acc);
#pragma unroll
    for (int mi = 0; mi < 2; ++mi)
#pragma unroll
        for (int ni = 0; ni < 2; ++ni) {
            const int row = mi * 16 + ((lane >> 4) << 2);
            const int col = ni * 16 + (lane & 15);
#pragma unroll
            for (int r = 0; r < 4; ++r)
                *(float*)(scrw + (row + r) * 144 + (col << 2)) = acc[mi][ni][r];
        }
    asm volatile("s_waitcnt lgkmcnt(0)" ::: "memory");
    const int rr = lane >> 1, hf = lane & 1;
    float* dst = pred_all + (size_t)s * (BAT * NIN)
               + (size_t)(bh * 256 + w * 32 + rr) * NIN + n0p + hf * 16;
#pragma unroll
    for (int t4 = 0; t4 < 4; ++t4) {
        f32x4 v = *(const f32x4*)(scrw + rr * 144 + hf * 64 + t4 * 16);
        const float4 b4 = *(const float4*)(bp + n0p + hf * 16 + t4 * 4);
        v[0] += b4.x; v[1] += b4.y; v[2] += b4.z; v[3] += b4.w;
        *(f32x4*)(dst + t4 * 4) = v;
    }
}

__global__ __launch_bounds__(256) void transpose_out(const float* __restrict__ pred_all,
                                                     float* __restrict__ out) {
    __shared__ float tl[32][65];
    const int base = blockIdx.x * 64;
    const int tid = threadIdx.x;
    for (int i = tid; i < 32 * 64; i += 256) {
        int s = i >> 6, f = i & 63;
        tl[s][f] = pred_all[(size_t)s * (BAT * NIN) + base + f];
    }
    __syncthreads();
    for (int i = tid; i < 64 * 32; i += 256) {
        int f = i >> 5, s = i & 31;
        out[(size_t)(base + f) * HOR + s] = tl[s][f];
    }
}

// ---------------- host ----------------

extern "C" void kernel_launch(void* const* d_in, const int* in_sizes, int n_in,
                              void* d_out, int out_size, void* d_ws, size_t ws_size,
                              hipStream_t stream) {
    (void)in_sizes; (void)n_in; (void)out_size; (void)ws_size;
    const float* window = (const float*)d_in[0];
    const float* Wih0 = (const float*)d_in[1];
    const float* Whh0 = (const float*)d_in[2];
    const float* bih0 = (const float*)d_in[3];
    const float* bhh0 = (const float*)d_in[4];
    const float* Wih1 = (const float*)d_in[5];
    const float* Whh1 = (const float*)d_in[6];
    const float* bih1 = (const float*)d_in[7];
    const float* bhh1 = (const float*)d_in[8];
    const float* Wc1i = (const float*)d_in[9];
    const float* Wc1h = (const float*)d_in[10];
    const float* bc1i = (const float*)d_in[11];
    const float* bc1h = (const float*)d_in[12];
    const float* Wc2i = (const float*)d_in[13];
    const float* Wc2h = (const float*)d_in[14];
    const float* bc2i = (const float*)d_in[15];
    const float* bc2h = (const float*)d_in[16];
    const float* Wp   = (const float*)d_in[17];
    const float* bp   = (const float*)d_in[18];
    const float* enc_mask   = (const float*)d_in[19];
    const float* dec_h_mask = (const float*)d_in[20];
    const float* dec_c_mask = (const float*)d_in[21];
    float* out = (float*)d_out;

    char* base = (char*)d_ws;
    size_t off = 0;
    auto take = [&](size_t bytes) -> char* {
        off = (off + 255) & ~(size_t)255;
        char* r = base + off; off += bytes; return r;
    };
    short* W2e0 = (short*)take((size_t)2048 * 640 * 2);
    short* W2e1 = (short*)take((size_t)2048 * 1024 * 2);
    short* W2d1 = (short*)take((size_t)2048 * 1024 * 2);
    short* W2d2 = (short*)take((size_t)2048 * 1024 * 2);
    short* W2p  = (short*)take((size_t)128 * 512 * 2);
    float* Wfuse = (float*)take((size_t)2048 * 512 * 4);
    float* badd  = (float*)take((size_t)2048 * 4);
    float* bias0 = (float*)take((size_t)2048 * 4);
    float* bias1 = (float*)take((size_t)2048 * 4);
    float* biasd1 = (float*)take((size_t)2048 * 4);
    float* biasd2 = (float*)take((size_t)2048 * 4);
    short* hBall0 = (short*)take(SLB);
    float* pred_all = (float*)take((size_t)HOR * BAT * NIN * 4);
    unsigned* bars = (unsigned*)take(16384);
    short* X2t = (short*)take((size_t)TST * 65536 * 2);
    short* hA0 = (short*)take(SLB);
    short* hA1 = (short*)take(SLB);
    short* hd0 = (short*)take(SLB);
    short* hd1 = (short*)take(SLB);
    short* hB0 = (short*)take(SLB);
    short* hB1 = (short*)take(SLB);
    short* hBallR = X2t;   // decoder h-history overlaps dead X2 region (15.5MB <= 16MB)

    // prep (re-done every call; deterministic)
    prep_fuse<<<(2048 * 512 + 255) / 256, 256, 0, stream>>>(Wc1i, Wp, Wfuse);
    prep_badd<<<8, 256, 0, stream>>>(Wc1i, bp, badd);
    prep_wp<<<(128 * 512 + 255) / 256, 256, 0, stream>>>(Wp, W2p);
    prep_w<<<(2048 * 640 + 255) / 256, 256, 0, stream>>>(Wih0, Whh0, W2e0, NIN, 640);
    prep_w<<<(2048 * 1024 + 255) / 256, 256, 0, stream>>>(Wih1, Whh1, W2e1, HID, 1024);
    prep_w<<<(2048 * 1024 + 255) / 256, 256, 0, stream>>>(Wfuse, Wc1h, W2d1, HID, 1024);
    prep_w<<<(2048 * 1024 + 255) / 256, 256, 0, stream>>>(Wc2i, Wc2h, W2d2, HID, 1024);
    prep_bias<<<8, 256, 0, stream>>>(bih0, bhh0, nullptr, bias0);
    prep_bias<<<8, 256, 0, stream>>>(bih1, bhh1, nullptr, bias1);
    prep_bias<<<8, 256, 0, stream>>>(bc1i, bc1h, badd, biasd1);
    prep_bias<<<8, 256, 0, stream>>>(bc2i, bc2h, nullptr, biasd2);
    prep_x<<<(int)(((size_t)TST * BAT * NIN + 255) / 256), 256, 0, stream>>>(window, X2t);
    hipMemsetAsync(hA0, 0, SLB, stream);
    hipMemsetAsync(hB0, 0, SLB, stream);
    hipMemsetAsync(bars, 0, 16384, stream);

    hipFuncSetAttribute((const void*)&persist_kernel,
                        hipFuncAttributeMaxDynamicSharedMemorySize, 163840);
    persist_kernel<<<256, 256, 147456, stream>>>(
        X2t, W2e0, W2e1, W2d1, W2d2,
        hA0, hA1, hd0, hd1, hB0, hB1,
        hBall0, hBallR,
        bias0, bias1, biasd1, biasd2,
        enc_mask, dec_h_mask, dec_c_mask, bars);

    hipFuncSetAttribute((const void*)&proj_kernel,
                        hipFuncAttributeMaxDynamicSharedMemorySize, 69632);
    proj_kernel<<<256, 512, 69632, stream>>>(hBall0, hBallR, W2p, bp, pred_all);

    transpose_out<<<(BAT * NIN) / 64, 256, 0, stream>>>(pred_all, out);
}

// Round 14
// 1736.396 us; speedup vs baseline: 1.3202x; 1.0299x over previous
//
#include <hip/hip_runtime.h>
#include <math.h>

#define HID 512
#define BAT 512
#define NIN 128
#define TST 128
#define HOR 32
#define SBZ ((size_t)BAT * HID)
#define SL 262144            // shorts per h-slot (512x512 bf16)
#define SLB 524288           // bytes per h-slot

using bf16x8 = __attribute__((ext_vector_type(8))) __bf16;
using f32x4  = __attribute__((ext_vector_type(4))) float;

__device__ __forceinline__ float sigf(float x) { return 1.0f / (1.0f + __expf(-x)); }
__device__ __forceinline__ float tanhfast(float x) { return 1.0f - 2.0f / (__expf(2.0f * x) + 1.0f); }

__device__ __forceinline__ short f2bf(float x) {
    union { float f; unsigned u; } v; v.f = x;
    unsigned r = (v.u + 0x7FFFu + ((v.u >> 16) & 1u)) >> 16;
    return (short)r;
}
__device__ __forceinline__ float bf2f(short s) {
    union { unsigned u; float f; } v; v.u = ((unsigned)(unsigned short)s) << 16;
    return v.f;
}
__device__ __forceinline__ bf16x8 asbf(f32x4 v) {
    union { f32x4 f; bf16x8 b; } u; u.f = v; return u.b;
}

// Pair barrier: 64 blocks (one mtile pair), 8 leaves x 8 + root + flag. Fence-free
// (sc0sc1 data path, r10-verified). b = pair-private 4KB region.
__device__ __forceinline__ void pbar(unsigned* b, int sub, unsigned ep) {
    __syncthreads();
    if (threadIdx.x == 0) {
        unsigned* leaf = b + (sub >> 3) * 32;
        unsigned* root = b + 512;
        unsigned* flag = b + 544;
        unsigned old = __hip_atomic_fetch_add(leaf, 1u, __ATOMIC_RELAXED, __HIP_MEMORY_SCOPE_AGENT);
        if (old == 8u * ep - 1u) {
            unsigned ro = __hip_atomic_fetch_add(root, 1u, __ATOMIC_RELAXED, __HIP_MEMORY_SCOPE_AGENT);
            if (ro == 8u * ep - 1u)
                __hip_atomic_store(flag, ep, __ATOMIC_RELAXED, __HIP_MEMORY_SCOPE_AGENT);
        }
        int spin = 0;
        while (__hip_atomic_load(flag, __ATOMIC_RELAXED, __HIP_MEMORY_SCOPE_AGENT) < ep) {
            __builtin_amdgcn_s_sleep(1);
            if (((++spin) & 63) == 0)
                __hip_atomic_fetch_add(flag, 0u, __ATOMIC_RELAXED, __HIP_MEMORY_SCOPE_AGENT);
        }
    }
    __syncthreads();
}

// Global barrier (r10-verified gbar3), used ONCE at the enc->dec transition.
__device__ __forceinline__ void gbar3(unsigned* bar, int bid, unsigned ep) {
    __syncthreads();
    if (threadIdx.x == 0) {
        unsigned* leaf = bar + ((unsigned)bid >> 3) * 32;
        unsigned* root = bar + 1024;
        unsigned* flag = bar + 1056;
        unsigned old = __hip_atomic_fetch_add(leaf, 1u, __ATOMIC_RELAXED, __HIP_MEMORY_SCOPE_AGENT);
        if (old == 8u * ep - 1u) {
            unsigned ro = __hip_atomic_fetch_add(root, 1u, __ATOMIC_RELAXED, __HIP_MEMORY_SCOPE_AGENT);
            if (ro == 32u * ep - 1u)
                __hip_atomic_store(flag, ep, __ATOMIC_RELAXED, __HIP_MEMORY_SCOPE_AGENT);
        }
        int spin = 0;
        while (__hip_atomic_load(flag, __ATOMIC_RELAXED, __HIP_MEMORY_SCOPE_AGENT) < ep) {
            __builtin_amdgcn_s_sleep(1);
            if (((++spin) & 63) == 0)
                __hip_atomic_fetch_add(flag, 0u, __ATOMIC_RELAXED, __HIP_MEMORY_SCOPE_AGENT);
        }
    }
    __syncthreads();
}

// ---------------- prep kernels (r11-verified) ----------------

__global__ __launch_bounds__(256) void prep_w(const float* __restrict__ Wih,
                                              const float* __restrict__ Whh,
                                              short* __restrict__ W2, int Kx, int Kp) {
    size_t i = (size_t)blockIdx.x * 256 + threadIdx.x;
    if (i >= (size_t)2048 * Kp) return;
    int np = (int)(i / Kp), kp = (int)(i % Kp);
    int u = np >> 2, gate = np & 3;
    int on = gate * HID + u;
    float w = (kp < Kx) ? Wih[(size_t)on * Kx + kp] : Whh[(size_t)on * HID + (kp - Kx)];
    W2[i] = f2bf(w);
}

__global__ __launch_bounds__(256) void prep_x(const float* __restrict__ window,
                                              short* __restrict__ X2t) {
    size_t i = (size_t)blockIdx.x * 256 + threadIdx.x;
    if (i >= (size_t)TST * BAT * NIN) return;
    int n = (int)(i & 127);
    int b = (int)((i >> 7) & 511);
    int t = (int)(i >> 16);
    float x = window[(size_t)b * (TST * NIN) + (size_t)t * NIN + n];
    int rg = b >> 4;
    int l = (b & 15) + (((n >> 3) & 3) << 4);
    int e = n & 7;
    size_t base = (size_t)t * 65536 + ((size_t)(rg * 4 + (n >> 5)) << 9) + l * 8 + e;
    X2t[base] = f2bf(x);
}

__global__ __launch_bounds__(256) void prep_fuse(const float* __restrict__ Wc1i,
                                                 const float* __restrict__ Wp,
                                                 float* __restrict__ Wfuse) {
    size_t i = (size_t)blockIdx.x * 256 + threadIdx.x;
    if (i >= (size_t)2048 * 512) return;
    int on = (int)(i >> 9), k = (int)(i & 511);
    float s = 0.f;
    for (int n = 0; n < NIN; ++n) s += Wc1i[(size_t)on * NIN + n] * Wp[(size_t)n * HID + k];
    Wfuse[i] = s;
}

__global__ __launch_bounds__(256) void prep_badd(const float* __restrict__ Wc1i,
                                                 const float* __restrict__ bp,
                                                 float* __restrict__ badd) {
    int on = blockIdx.x * 256 + threadIdx.x;
    if (on >= 2048) return;
    float s = 0.f;
    for (int n = 0; n < NIN; ++n) s += Wc1i[(size_t)on * NIN + n] * bp[n];
    badd[on] = s;
}

__global__ __launch_bounds__(256) void prep_bias(const float* __restrict__ bih,
                                                 const float* __restrict__ bhh,
                                                 const float* __restrict__ badd,
                                                 float* __restrict__ bout) {
    int np = blockIdx.x * 256 + threadIdx.x;
    if (np >= 2048) return;
    int on = (np & 3) * HID + (np >> 2);
    float v = bih[on] + bhh[on];
    if (badd) v += badd[on];
    bout[np] = v;
}

__global__ __launch_bounds__(256) void prep_wp(const float* __restrict__ Wp,
                                               short* __restrict__ W2p) {
    int i = blockIdx.x * 256 + threadIdx.x;
    if (i >= 128 * 512) return;
    W2p[i] = f2bf(Wp[i]);
}

// ---------------- device building blocks ----------------

template<bool SC>
__device__ __forceinline__ void gl16(f32x4& q, const char* p) {
    if constexpr (SC)
        asm volatile("global_load_dwordx4 %0, %1, off sc0 sc1" : "=v"(q) : "v"(p));
    else
        asm volatile("global_load_dwordx4 %0, %1, off" : "=v"(q) : "v"(p));
}

// 32-row resident W (proj): lds[j*512 + r*16]
__device__ __forceinline__ void load_wres32(char* lds, const short* Wg, int K) {
    const int tid = threadIdx.x;
    const int r = tid >> 4;
    const int cnt = K >> 7;
    const int jb = (tid & 15) * cnt;
    for (int q = 0; q < cnt; ++q) {
        int j = jb + q;
        bf16x8 v = *(const bf16x8*)(Wg + (size_t)r * K + j * 8);
        *(bf16x8*)(lds + j * 512 + r * 16) = v;
    }
}

// 64-row resident W (persist, 256 threads): lds[j*1024 + r*16], r=0..63
__device__ __forceinline__ void load_wres64(char* lds, const short* Wg, int K) {
    const int r = threadIdx.x >> 2, jg = threadIdx.x & 3;
    for (int q = 0; q < (K >> 5); ++q) {
        int j = jg + (q << 2);
        bf16x8 v = *(const bf16x8*)(Wg + (size_t)r * K + j * 8);
        *(bf16x8*)(lds + (size_t)j * 1024 + r * 16) = v;
    }
}

// mask prefetch (asm loads BEFORE counted loads: oldest-first drain keeps vmcnt math safe)
__device__ __forceinline__ void pre_mask_asm(const float* msk, int mrow, int u0, float o[4]) {
    const int lane = threadIdx.x & 63;
    const float* p = msk + (size_t)(mrow + ((lane >> 3) << 2)) * HID + u0 + (lane & 7);
#pragma unroll
    for (int r = 0; r < 4; ++r)
        asm volatile("global_load_dword %0, %1, off" : "=v"(o[r]) : "v"(p + (size_t)r * HID));
}

// Wave GEMM 32(m) x 64(n') over chunked A (1KB contiguous loads); counted-vmcnt D=16;
// W from 64-row resident LDS. SC0/SC1: coherence mode per operand.
template<int C0, int C1, bool SC0, bool SC1>
__device__ __forceinline__ void gemm64(
    const char* wres, const short* a0t, const short* a1t,
    int mb, f32x4 acc[2][4])
{
    constexpr int NKC = C0 + C1;
    constexpr int D = 16;
    const int lane = threadIdx.x & 63;
    const int arow = lane & 15, akg = lane >> 4;
    const size_t lb = (size_t)lane << 4;
    const char* base0 = (const char*)a0t;
    const char* base1 = (const char*)a1t;
    auto cptr = [&](int kc, int fh) -> const char* {
        return (kc < C0)
            ? base0 + (((size_t)(mb * 2 + fh) * C0 + kc) << 10) + lb
            : base1 + (((size_t)(mb * 2 + fh) * C1 + (kc - C0)) << 10) + lb;
    };
    f32x4 q0[D], q1[D];
#pragma unroll
    for (int i = 0; i < D; ++i) {
        if (i < C0) { gl16<SC0>(q0[i], cptr(i, 0)); gl16<SC0>(q1[i], cptr(i, 1)); }
        else        { gl16<SC1>(q0[i], cptr(i, 0)); gl16<SC1>(q1[i], cptr(i, 1)); }
    }
#pragma unroll
    for (int kc = 0; kc < NKC; ++kc) {
        const int sl = kc % D;
        asm volatile("s_waitcnt vmcnt(%2)"
                     : "+v"(q0[sl]), "+v"(q1[sl])
                     : "i"((2 * ((NKC - kc) < D ? (NKC - kc) : D)) - 2));
        const bf16x8 fa0 = asbf(q0[sl]);
        const bf16x8 fa1 = asbf(q1[sl]);
        if (kc + D < NKC) {
            if (kc + D < C0) { gl16<SC0>(q0[sl], cptr(kc + D, 0)); gl16<SC0>(q1[sl], cptr(kc + D, 1)); }
            else             { gl16<SC1>(q0[sl], cptr(kc + D, 0)); gl16<SC1>(q1[sl], cptr(kc + D, 1)); }
        }
        const char* wrow = wres + (size_t)((kc << 2) + akg) * 1024;
        bf16x8 fb[4];
#pragma unroll
        for (int nj = 0; nj < 4; ++nj)
            fb[nj] = *(const bf16x8*)(wrow + ((nj * 16 + arow) << 4));
#pragma unroll
        for (int nj = 0; nj < 4; ++nj) {
            acc[0][nj] = __builtin_amdgcn_mfma_f32_16x16x32_bf16(fa0, fb[nj], acc[0][nj], 0, 0, 0);
            acc[1][nj] = __builtin_amdgcn_mfma_f32_16x16x32_bf16(fa1, fb[nj], acc[1][nj], 0, 0, 0);
        }
    }
    asm volatile("s_waitcnt vmcnt(0)");
}

// Wave LSTM epilogue over 32 rows x 64 n' in two 32-wide passes (r12/r13-verified).
__device__ __forceinline__ void cell_epi64(
    char* scrw, f32x4 acc[2][4], float creg[2][4], int mb, int np0,
    const float* bias_p, const float* mh, const float* mc, const float* ma,
    short* h_out, short* h_aux)
{
    const int lane = threadIdx.x & 63;
#pragma unroll
    for (int p = 0; p < 2; ++p) {
        const int np0p = np0 + (p << 5);
#pragma unroll
        for (int mi = 0; mi < 2; ++mi)
#pragma unroll
            for (int nj = 0; nj < 2; ++nj) {
                const int row = mi * 16 + ((lane >> 4) << 2);
                const int col = nj * 16 + (lane & 15);
#pragma unroll
                for (int r = 0; r < 4; ++r)
                    *(float*)(scrw + (row + r) * 128 + (col << 2)) = acc[mi][p * 2 + nj][r];
            }
        asm volatile("s_waitcnt lgkmcnt(0)" ::: "memory");
        const int ul = lane & 7, g = lane >> 3;
        f32x4 gv[4];
#pragma unroll
        for (int r = 0; r < 4; ++r)
            gv[r] = *(const f32x4*)(scrw + ((g << 2) + r) * 128 + (ul << 4));
        asm volatile("s_waitcnt lgkmcnt(0)" ::: "memory");
        const float4 bs = *(const float4*)(bias_p + np0p + (ul << 2));
#pragma unroll
        for (int r = 0; r < 4; ++r) {
            const int m = (g << 2) + r;
            const int fh = m >> 4, r16 = m & 15;
            const float gi = gv[r][0] + bs.x, gf = gv[r][1] + bs.y;
            const float gg = gv[r][2] + bs.z, go = gv[r][3] + bs.w;
            const float cn = sigf(gf) * creg[p][r] + sigf(gi) * tanhfast(gg);
            const float h  = sigf(go) * tanhfast(cn);
            creg[p][r] = mc ? cn * mc[p * 4 + r] : cn;
            const float hm = mh ? h * mh[p * 4 + r] : h;
            const int idx2 = (r16 << 3) + ul;
            *(short*)(scrw + fh * 256 + idx2 * 2) = f2bf(hm);
            if (h_aux)
                *(short*)(scrw + 512 + fh * 256 + idx2 * 2) = f2bf(h * ma[p * 4 + r]);
        }
        const int u0p = np0p >> 2;
        const int c_hi = u0p >> 5, gsub = (u0p >> 3) & 3;
        unsigned vmain[2], vaux[2];
#pragma unroll
        for (int s = 0; s < 2; ++s)
            vmain[s] = *(const unsigned*)(scrw + s * 256 + (lane << 2));
        if (h_aux)
#pragma unroll
            for (int s = 0; s < 2; ++s)
                vaux[s] = *(const unsigned*)(scrw + 512 + s * 256 + (lane << 2));
        asm volatile("s_waitcnt lgkmcnt(0)" ::: "memory");
#pragma unroll
        for (int s = 0; s < 2; ++s) {
            const unsigned* dst = (const unsigned*)(h_out
                + ((size_t)((mb * 2 + s) * 16 + c_hi) << 9) + (gsub << 7)) + lane;
            asm volatile("global_store_dword %0, %1, off sc0 sc1" :: "v"(dst), "v"(vmain[s]));
        }
        if (h_aux)
#pragma unroll
            for (int s = 0; s < 2; ++s) {
                const unsigned* dst = (const unsigned*)(h_aux
                    + ((size_t)((mb * 2 + s) * 16 + c_hi) << 9) + (gsub << 7)) + lane;
                asm volatile("global_store_dword %0, %1, off sc0 sc1" :: "v"(dst), "v"(vaux[s]));
            }
    }
}

// ---------------- persistent kernel: grid 256 x 256thr, pair-barrier sync ----------------
// Role: xcd=bid&7: half = xcd>>2, mtile = xcd&3 (m0=mtile*128), ntile=bid>>3 (np0=ntile*64).
// All data flows are row-partitioned by mtile -> sync domain = 64-block pair (both halves
// of one mtile). One GLOBAL barrier at enc->dec transition (hBallR overlays X2t).

__global__ void __launch_bounds__(256, 1) persist_kernel(
    const short* __restrict__ X2t,
    const short* __restrict__ W0, const short* __restrict__ W1,
    const short* __restrict__ Wd1, const short* __restrict__ Wd2,
    short* hA0, short* hA1, short* hd0, short* hd1, short* hB0, short* hB1,
    short* hBall0, short* hBallR,
    const float* __restrict__ bias0, const float* __restrict__ bias1,
    const float* __restrict__ biasd1, const float* __restrict__ biasd2,
    const float* __restrict__ enc_mask, const float* __restrict__ dec_h_mask,
    const float* __restrict__ dec_c_mask, unsigned* bar)
{
    extern __shared__ __align__(16) char lds[];
    const int bid = blockIdx.x;
    const int xcd = bid & 7;
    const int half = xcd >> 2;
    const int mtile = xcd & 3;
    const int m0 = mtile * 128;
    const int ntile = bid >> 3;                 // 0..31
    const int np0 = ntile * 64;
    const int u0 = np0 >> 2;
    const int w = threadIdx.x >> 6;             // 0..3
    const int mb = (m0 >> 5) + w;
    const int mrow = m0 + (w << 5);
    char* scrw = lds + 131072 + (w << 12);
    float creg[2][4] = {{0.f,0.f,0.f,0.f},{0.f,0.f,0.f,0.f}};

    unsigned* pb = bar + mtile * 1024;          // pair-private 4KB region
    unsigned* gb = bar + 4096;                  // global barrier region
    const int sub = (half << 5) | ntile;        // 0..63 within pair

    auto hA_rd = [&](int t) -> const short* { return (t & 1) ? hA1 : hA0; };
    auto hA_wr = [&](int t) -> short* { return (t & 1) ? hA0 : hA1; };
    auto hd_at = [&](int t) -> short* { return (t & 1) ? hd1 : hd0; };
    auto hB_rd = [&](int t) -> const short* { return (t & 1) ? hB1 : hB0; };
    auto hB_wr = [&](int t) -> short* { return (t & 1) ? hB0 : hB1; };
    auto decA_at = [&](int i) -> short* { return (i & 1) ? hA1 : hA0; };
    auto hball = [&](int i) -> short* { return (i == 0) ? hBall0 : hBallR + (size_t)(i - 1) * SL; };

    // ---- encoder ----
    load_wres64(lds, (half ? W1 : W0) + (size_t)np0 * (half ? 1024 : 640), half ? 1024 : 640);
    __syncthreads();
    unsigned ep = 0;
    for (int tt = 0; tt <= TST; ++tt) {
        if (half == 0) {
            if (tt < TST) {
                const int t = tt;
                float ma[8];
                pre_mask_asm(enc_mask + (size_t)t * SBZ, mrow, u0, ma);
                pre_mask_asm(enc_mask + (size_t)t * SBZ, mrow, u0 + 8, ma + 4);
                f32x4 acc[2][4];
#pragma unroll
                for (int a = 0; a < 2; ++a)
#pragma unroll
                    for (int b2 = 0; b2 < 4; ++b2) acc[a][b2] = (f32x4){0.f, 0.f, 0.f, 0.f};
                gemm64<4, 16, false, true>(lds, X2t + (size_t)t * 65536, hA_rd(t), mb, acc);
                cell_epi64(scrw, acc, creg, mb, np0, bias0, nullptr, nullptr, ma,
                           hA_wr(t), hd_at(t));
            }
        } else {
            if (tt >= 1) {
                const int t = tt - 1;
                f32x4 acc[2][4];
#pragma unroll
                for (int a = 0; a < 2; ++a)
#pragma unroll
                    for (int b2 = 0; b2 < 4; ++b2) acc[a][b2] = (f32x4){0.f, 0.f, 0.f, 0.f};
                gemm64<16, 16, true, true>(lds, hd_at(t), hB_rd(t), mb, acc);
                short* outp = (t == TST - 1) ? hBall0 : hB_wr(t);
                cell_epi64(scrw, acc, creg, mb, np0, bias1, nullptr, nullptr, nullptr,
                           outp, nullptr);
            }
        }
        pbar(pb, sub, ++ep);
    }

    // enc->dec transition: GLOBAL barrier (decoder's hBallR overlays X2t, which
    // encoder blocks of other pairs may still be reading until here).
    gbar3(gb, bid, 1u);

    // ---- decoder ----
    load_wres64(lds, (half ? Wd2 : Wd1) + (size_t)np0 * 1024, 1024);
    __syncthreads();
    for (int s = 0; s < HOR - 1; ++s) {
        if (half == 0) {
            float mh[8], mc[8];
            pre_mask_asm(dec_h_mask + (size_t)s * SBZ, mrow, u0, mh);
            pre_mask_asm(dec_h_mask + (size_t)s * SBZ, mrow, u0 + 8, mh + 4);
            pre_mask_asm(dec_c_mask + (size_t)s * SBZ, mrow, u0, mc);
            pre_mask_asm(dec_c_mask + (size_t)s * SBZ, mrow, u0 + 8, mc + 4);
            f32x4 acc[2][4];
#pragma unroll
            for (int a = 0; a < 2; ++a)
#pragma unroll
                for (int b2 = 0; b2 < 4; ++b2) acc[a][b2] = (f32x4){0.f, 0.f, 0.f, 0.f};
            gemm64<16, 16, true, true>(lds, hball(s), decA_at(s), mb, acc);
            cell_epi64(scrw, acc, creg, mb, np0, biasd1, mh, mc, nullptr,
                       decA_at(s + 1), nullptr);
        }
        pbar(pb, sub, ++ep);
        if (half == 1) {
            f32x4 acc[2][4];
#pragma unroll
            for (int a = 0; a < 2; ++a)
#pragma unroll
                for (int b2 = 0; b2 < 4; ++b2) acc[a][b2] = (f32x4){0.f, 0.f, 0.f, 0.f};
            gemm64<16, 16, true, true>(lds, decA_at(s + 1), hball(s), mb, acc);
            cell_epi64(scrw, acc, creg, mb, np0, biasd2, nullptr, nullptr, nullptr,
                       hball(s + 1), nullptr);
        }
        pbar(pb, sub, ++ep);
    }
}

// ---------------- batched projection (r11-verified; cached loads — persist done) --------

template<int C0, int C1>
__device__ __forceinline__ void gemm_pipeP(
    const char* wres, const short* a0t, const short* a1t,
    int mb, f32x4 acc[2][2])
{
    constexpr int NKC = C0 + C1;
    constexpr int D = 16;
    const int lane = threadIdx.x & 63;
    const int arow = lane & 15, akg = lane >> 4;
    const size_t lb = (size_t)lane << 4;
    const char* base0 = (const char*)a0t;
    const char* base1 = (const char*)a1t;
    auto cptr = [&](int kc, int fh) -> const char* {
        return (kc < C0)
            ? base0 + (((size_t)(mb * 2 + fh) * C0 + kc) << 10) + lb
            : base1 + (((size_t)(mb * 2 + fh) * C1 + (kc - C0)) << 10) + lb;
    };
    f32x4 q0[D], q1[D];
#pragma unroll
    for (int i = 0; i < D; ++i) {
        gl16<false>(q0[i], cptr(i, 0));
        gl16<false>(q1[i], cptr(i, 1));
    }
#pragma unroll
    for (int kc = 0; kc < NKC; ++kc) {
        const int sl = kc % D;
        asm volatile("s_waitcnt vmcnt(%2)"
                     : "+v"(q0[sl]), "+v"(q1[sl])
                     : "i"((2 * ((NKC - kc) < D ? (NKC - kc) : D)) - 2));
        const bf16x8 fa0 = asbf(q0[sl]);
        const bf16x8 fa1 = asbf(q1[sl]);
        if (kc + D < NKC) {
            gl16<false>(q0[sl], cptr(kc + D, 0));
            gl16<false>(q1[sl], cptr(kc + D, 1));
        }
        const char* wrow = wres + (size_t)(((kc << 2) + akg) << 9);
        const bf16x8 fb0 = *(const bf16x8*)(wrow + (arow << 4));
        const bf16x8 fb1 = *(const bf16x8*)(wrow + ((16 + arow) << 4));
        acc[0][0] = __builtin_amdgcn_mfma_f32_16x16x32_bf16(fa0, fb0, acc[0][0], 0, 0, 0);
        acc[0][1] = __builtin_amdgcn_mfma_f32_16x16x32_bf16(fa0, fb1, acc[0][1], 0, 0, 0);
        acc[1][0] = __builtin_amdgcn_mfma_f32_16x16x32_bf16(fa1, fb0, acc[1][0], 0, 0, 0);
        acc[1][1] = __builtin_amdgcn_mfma_f32_16x16x32_bf16(fa1, fb1, acc[1][1], 0, 0, 0);
    }
    asm volatile("s_waitcnt vmcnt(0)");
}

__global__ void __launch_bounds__(512, 2) proj_kernel(
    const short* hBall0, const short* hBallR, const short* __restrict__ W2p,
    const float* __restrict__ bp, float* __restrict__ pred_all)
{
    extern __shared__ __align__(16) char lds[];
    const int bid = blockIdx.x;
    const int s = bid >> 3, q = bid & 7;
    const int bh = q >> 2, n0p = (q & 3) * 32;
    load_wres32(lds, W2p + (size_t)n0p * 512, 512);
    const int w = threadIdx.x >> 6, lane = threadIdx.x & 63;
    char* scrw = lds + 32768 + w * 4608;
    const int mb = bh * 8 + w;
    const short* A = (s == 0) ? hBall0 : hBallR + (size_t)(s - 1) * SL;
    __syncthreads();
    f32x4 acc[2][2];
#pragma unroll
    for (int a = 0; a < 2; ++a)
#pragma unroll
        for (int b2 = 0; b2 < 2; ++b2) acc[a][b2] = (f32x4){0.f, 0.f, 0.f, 0.f};
    gemm_pipeP<16, 0>(lds, A, A, mb, acc);
#pragma unroll
    for (int mi = 0; mi < 2; ++mi)
#pragma unroll
        for (int ni = 0; ni < 2; ++ni) {
            const int row = mi * 16 + ((lane >> 4) << 2);
            const int col = ni * 16 + (lane & 15);
#pragma unroll
            for (int r = 0; r < 4; ++r)
                *(float*)(scrw + (row + r) * 144 + (col << 2)) = acc[mi][ni][r];
        }
    asm volatile("s_waitcnt lgkmcnt(0)" ::: "memory");
    const int rr = lane >> 1, hf = lane & 1;
    float* dst = pred_all + (size_t)s * (BAT * NIN)
               + (size_t)(bh * 256 + w * 32 + rr) * NIN + n0p + hf * 16;
#pragma unroll
    for (int t4 = 0; t4 < 4; ++t4) {
        f32x4 v = *(const f32x4*)(scrw + rr * 144 + hf * 64 + t4 * 16);
        const float4 b4 = *(const float4*)(bp + n0p + hf * 16 + t4 * 4);
        v[0] += b4.x; v[1] += b4.y; v[2] += b4.z; v[3] += b4.w;
        *(f32x4*)(dst + t4 * 4) = v;
    }
}

__global__ __launch_bounds__(256) void transpose_out(const float* __restrict__ pred_all,
                                                     float* __restrict__ out) {
    __shared__ float tl[32][65];
    const int base = blockIdx.x * 64;
    const int tid = threadIdx.x;
    for (int i = tid; i < 32 * 64; i += 256) {
        int s = i >> 6, f = i & 63;
        tl[s][f] = pred_all[(size_t)s * (BAT * NIN) + base + f];
    }
    __syncthreads();
    for (int i = tid; i < 64 * 32; i += 256) {
        int f = i >> 5, s = i & 31;
        out[(size_t)(base + f) * HOR + s] = tl[s][f];
    }
}

// ---------------- host ----------------

extern "C" void kernel_launch(void* const* d_in, const int* in_sizes, int n_in,
                              void* d_out, int out_size, void* d_ws, size_t ws_size,
                              hipStream_t stream) {
    (void)in_sizes; (void)n_in; (void)out_size; (void)ws_size;
    const float* window = (const float*)d_in[0];
    const float* Wih0 = (const float*)d_in[1];
    const float* Whh0 = (const float*)d_in[2];
    const float* bih0 = (const float*)d_in[3];
    const float* bhh0 = (const float*)d_in[4];
    const float* Wih1 = (const float*)d_in[5];
    const float* Whh1 = (const float*)d_in[6];
    const float* bih1 = (const float*)d_in[7];
    const float* bhh1 = (const float*)d_in[8];
    const float* Wc1i = (const float*)d_in[9];
    const float* Wc1h = (const float*)d_in[10];
    const float* bc1i = (const float*)d_in[11];
    const float* bc1h = (const float*)d_in[12];
    const float* Wc2i = (const float*)d_in[13];
    const float* Wc2h = (const float*)d_in[14];
    const float* bc2i = (const float*)d_in[15];
    const float* bc2h = (const float*)d_in[16];
    const float* Wp   = (const float*)d_in[17];
    const float* bp   = (const float*)d_in[18];
    const float* enc_mask   = (const float*)d_in[19];
    const float* dec_h_mask = (const float*)d_in[20];
    const float* dec_c_mask = (const float*)d_in[21];
    float* out = (float*)d_out;

    char* base = (char*)d_ws;
    size_t off = 0;
    auto take = [&](size_t bytes) -> char* {
        off = (off + 255) & ~(size_t)255;
        char* r = base + off; off += bytes; return r;
    };
    short* W2e0 = (short*)take((size_t)2048 * 640 * 2);
    short* W2e1 = (short*)take((size_t)2048 * 1024 * 2);
    short* W2d1 = (short*)take((size_t)2048 * 1024 * 2);
    short* W2d2 = (short*)take((size_t)2048 * 1024 * 2);
    short* W2p  = (short*)take((size_t)128 * 512 * 2);
    float* Wfuse = (float*)take((size_t)2048 * 512 * 4);
    float* badd  = (float*)take((size_t)2048 * 4);
    float* bias0 = (float*)take((size_t)2048 * 4);
    float* bias1 = (float*)take((size_t)2048 * 4);
    float* biasd1 = (float*)take((size_t)2048 * 4);
    float* biasd2 = (float*)take((size_t)2048 * 4);
    short* hBall0 = (short*)take(SLB);
    float* pred_all = (float*)take((size_t)HOR * BAT * NIN * 4);
    unsigned* bars = (unsigned*)take(32768);  // pairs @0..16KB, global @16KB
    short* X2t = (short*)take((size_t)TST * 65536 * 2);
    short* hA0 = (short*)take(SLB);
    short* hA1 = (short*)take(SLB);
    short* hd0 = (short*)take(SLB);
    short* hd1 = (short*)take(SLB);
    short* hB0 = (short*)take(SLB);
    short* hB1 = (short*)take(SLB);
    short* hBallR = X2t;   // decoder h-history overlaps dead X2 region (15.5MB <= 16MB)

    // prep (re-done every call; deterministic)
    prep_fuse<<<(2048 * 512 + 255) / 256, 256, 0, stream>>>(Wc1i, Wp, Wfuse);
    prep_badd<<<8, 256, 0, stream>>>(Wc1i, bp, badd);
    prep_wp<<<(128 * 512 + 255) / 256, 256, 0, stream>>>(Wp, W2p);
    prep_w<<<(2048 * 640 + 255) / 256, 256, 0, stream>>>(Wih0, Whh0, W2e0, NIN, 640);
    prep_w<<<(2048 * 1024 + 255) / 256, 256, 0, stream>>>(Wih1, Whh1, W2e1, HID, 1024);
    prep_w<<<(2048 * 1024 + 255) / 256, 256, 0, stream>>>(Wfuse, Wc1h, W2d1, HID, 1024);
    prep_w<<<(2048 * 1024 + 255) / 256, 256, 0, stream>>>(Wc2i, Wc2h, W2d2, HID, 1024);
    prep_bias<<<8, 256, 0, stream>>>(bih0, bhh0, nullptr, bias0);
    prep_bias<<<8, 256, 0, stream>>>(bih1, bhh1, nullptr, bias1);
    prep_bias<<<8, 256, 0, stream>>>(bc1i, bc1h, badd, biasd1);
    prep_bias<<<8, 256, 0, stream>>>(bc2i, bc2h, nullptr, biasd2);
    prep_x<<<(int)(((size_t)TST * BAT * NIN + 255) / 256), 256, 0, stream>>>(window, X2t);
    hipMemsetAsync(hA0, 0, SLB, stream);
    hipMemsetAsync(hB0, 0, SLB, stream);
    hipMemsetAsync(bars, 0, 32768, stream);

    hipFuncSetAttribute((const void*)&persist_kernel,
                        hipFuncAttributeMaxDynamicSharedMemorySize, 163840);
    persist_kernel<<<256, 256, 147456, stream>>>(
        X2t, W2e0, W2e1, W2d1, W2d2,
        hA0, hA1, hd0, hd1, hB0, hB1,
        hBall0, hBallR,
        bias0, bias1, biasd1, biasd2,
        enc_mask, dec_h_mask, dec_c_mask, bars);

    hipFuncSetAttribute((const void*)&proj_kernel,
                        hipFuncAttributeMaxDynamicSharedMemorySize, 69632);
    proj_kernel<<<256, 512, 69632, stream>>>(hBall0, hBallR, W2p, bp, pred_all);

    transpose_out<<<(BAT * NIN) / 64, 256, 0, stream>>>(pred_all, out);
}